// Round 3
// baseline (662.420 us; speedup 1.0000x reference)
//
#include <hip/hip_runtime.h>
#include <math.h>

typedef float  f32x4 __attribute__((ext_vector_type(4)));
typedef short  s16x8 __attribute__((ext_vector_type(8)));
typedef unsigned short u16;
typedef unsigned int u32;

// ---------- bf16 helpers ----------
static __device__ __forceinline__ u16 f32_to_bf16_rne(float f) {
    u32 u = __builtin_bit_cast(u32, f);
    u32 r = u + 0x7fffu + ((u >> 16) & 1u);
    return (u16)(r >> 16);
}
static __device__ __forceinline__ u16 f32_to_bf16_rhu(float f) {
    u32 u = __builtin_bit_cast(u32, f);
    return (u16)((u + 0x8000u) >> 16);
}
static __device__ __forceinline__ float bf16_to_f32(u16 h) {
    return __builtin_bit_cast(float, (u32)h << 16);
}

// async global->LDS 16B: lds dest = wave-uniform base + lane*16
static __device__ __forceinline__ void gl2lds16(const void* g, void* l) {
    __builtin_amdgcn_global_load_lds(
        (const __attribute__((address_space(1))) u32*)g,
        (__attribute__((address_space(3))) u32*)l, 16, 0, 0);
}

// ---------- 1) cast fp32 -> bf16 ----------
__global__ void k_cast(const float* __restrict__ in, u16* __restrict__ out) {
    int i = (blockIdx.x * 256 + threadIdx.x) * 4;
    float4 v = *reinterpret_cast<const float4*>(in + i);
    ushort4 u;
    u.x = f32_to_bf16_rne(v.x); u.y = f32_to_bf16_rne(v.y);
    u.z = f32_to_bf16_rne(v.z); u.w = f32_to_bf16_rne(v.w);
    *reinterpret_cast<ushort4*>(out + i) = u;
}

// ---------- 2) transpose + cast: W (R x C fp32) -> Wt (C x R bf16) ----------
__global__ void k_transpose_cast(const float* __restrict__ in, u16* __restrict__ out,
                                 int R, int C) {
    __shared__ __align__(16) float tile[64 * 68];
    const int ct = blockIdx.x, rt = blockIdx.y;
    const int t = threadIdx.x;
    const int tr = t >> 4;
    const int tc4 = (t & 15) * 4;
#pragma unroll
    for (int rn = 0; rn < 4; ++rn) {
        int r = rn * 16 + tr;
        float4 v = *reinterpret_cast<const float4*>(in + (size_t)(rt * 64 + r) * C + ct * 64 + tc4);
        *reinterpret_cast<float4*>(&tile[r * 68 + tc4]) = v;
    }
    __syncthreads();
#pragma unroll
    for (int rn = 0; rn < 4; ++rn) {
        int oc = rn * 16 + tr;
        ushort4 u;
        u.x = f32_to_bf16_rne(tile[(tc4 + 0) * 68 + oc]);
        u.y = f32_to_bf16_rne(tile[(tc4 + 1) * 68 + oc]);
        u.z = f32_to_bf16_rne(tile[(tc4 + 2) * 68 + oc]);
        u.w = f32_to_bf16_rne(tile[(tc4 + 3) * 68 + oc]);
        *reinterpret_cast<ushort4*>(out + (size_t)(ct * 64 + oc) * R + rt * 64 + tc4) = u;
    }
}

// ---------- 3) GEMM m97-style: C[M,N] = A[M,K] * Bt[N,K]^T ----------
// BK=64, global_load_lds dwordx4, XOR-swizzled LDS [128][64].
// ROPE: fused rotary embedding on the C-tile (qkv GEMM only, cols<4096).
template<bool BF16OUT, bool ROPE>
__global__ __launch_bounds__(256) void k_gemm_bt(const u16* __restrict__ Amat,
                                                 const u16* __restrict__ Bt,
                                                 void* __restrict__ Cout,
                                                 int M, int N, int K) {
    __shared__ __align__(16) u16 As[128 * 64];
    __shared__ __align__(16) u16 Bs[128 * 64];
    const int t = threadIdx.x;
    const int lane = t & 63, wave = t >> 6;
    const int m16 = lane & 15, qd = lane >> 4;
    const int wm = (wave >> 1) * 64, wn = (wave & 1) * 64;
    const size_t m0 = (size_t)blockIdx.y * 128, n0 = (size_t)blockIdx.x * 128;
    const int srow = lane >> 3;
    const int schunk = (lane & 7) ^ srow;

    f32x4 acc[4][4] = {};

    for (int k0 = 0; k0 < K; k0 += 64) {
#pragma unroll
        for (int j = 0; j < 4; ++j) {
            int rbase = j * 32 + wave * 8;
            int r = rbase + srow;
            gl2lds16(Amat + (m0 + r) * (size_t)K + k0 + schunk * 8, &As[rbase * 64]);
            gl2lds16(Bt   + (n0 + r) * (size_t)K + k0 + schunk * 8, &Bs[rbase * 64]);
        }
        __syncthreads();
#pragma unroll
        for (int kh = 0; kh < 2; ++kh) {
            s16x8 af[4], bf[4];
#pragma unroll
            for (int i = 0; i < 4; ++i) {
                int ra = wm + i * 16 + m16;
                int pa = (kh * 4 + qd) ^ (ra & 7);
                af[i] = *reinterpret_cast<const s16x8*>(&As[ra * 64 + pa * 8]);
                int rb = wn + i * 16 + m16;
                int pb = (kh * 4 + qd) ^ (rb & 7);
                bf[i] = *reinterpret_cast<const s16x8*>(&Bs[rb * 64 + pb * 8]);
            }
#pragma unroll
            for (int i = 0; i < 4; ++i)
#pragma unroll
                for (int jj = 0; jj < 4; ++jj)
                    acc[i][jj] = __builtin_amdgcn_mfma_f32_16x16x32_bf16(af[i], bf[jj], acc[i][jj], 0, 0, 0);
        }
        __syncthreads();
    }
    // C/D layout: col = lane&15, row = (lane>>4)*4 + reg
    if (ROPE && n0 < 4096) {
        float invf[4];
#pragma unroll
        for (int j = 0; j < 4; ++j) {
            int pi = ((int)(wn + j * 16 + m16) & 127) >> 1;   // head-local pair idx
            invf[j] = __expf(-0.14391156831f * (float)pi);    // 10000^(-pi/64)
        }
#pragma unroll
        for (int i = 0; i < 4; ++i)
#pragma unroll
            for (int j = 0; j < 4; ++j)
#pragma unroll
                for (int r = 0; r < 4; ++r) {
                    float v = acc[i][j][r];
                    float p = __shfl_xor(v, 1);   // pair partner (adjacent col)
                    size_t row = m0 + wm + i * 16 + qd * 4 + r;
                    float f = (float)(int)(row & 2047) * invf[j];
                    float sn, cs;
                    __sincosf(f, &sn, &cs);
                    float res = (m16 & 1) ? fmaf(p, sn, v * cs) : fmaf(v, cs, -p * sn);
                    size_t col = n0 + wn + j * 16 + m16;
                    ((u16*)Cout)[row * N + col] = f32_to_bf16_rne(res);
                }
    } else {
#pragma unroll
        for (int i = 0; i < 4; ++i)
#pragma unroll
            for (int j = 0; j < 4; ++j)
#pragma unroll
                for (int r = 0; r < 4; ++r) {
                    size_t row = m0 + wm + i * 16 + qd * 4 + r;
                    size_t col = n0 + wn + j * 16 + m16;
                    if (BF16OUT)
                        ((u16*)Cout)[row * N + col] = f32_to_bf16_rne(acc[i][j][r]);
                    else
                        ((float*)Cout)[row * N + col] = acc[i][j][r];
                }
    }
}

// ---------- 4) V -> V^T ----------
__global__ void k_transpose_v(const u16* __restrict__ qkv, u16* __restrict__ vt) {
    __shared__ u16 tile[64 * 68];
    const int st = blockIdx.x;
    const int bhd = blockIdx.y;
    const int bh = bhd >> 1, dt = bhd & 1;
    const u16* src = qkv + (size_t)(bh >> 4) * 2048 * 6144 + 4096 + (size_t)(bh & 15) * 128 + dt * 64;
    const int t = threadIdx.x, tr = t >> 4, tc4 = (t & 15) * 4;
#pragma unroll
    for (int rn = 0; rn < 4; ++rn) {
        int s = rn * 16 + tr;
        *reinterpret_cast<ushort4*>(&tile[s * 68 + tc4]) =
            *reinterpret_cast<const ushort4*>(src + (size_t)(st * 64 + s) * 6144 + tc4);
    }
    __syncthreads();
    u16* dst = vt + ((size_t)bh * 128 + dt * 64) * 2048 + st * 64;
#pragma unroll
    for (int rn = 0; rn < 4; ++rn) {
        int d = rn * 16 + tr;
        ushort4 u;
        u.x = tile[(tc4 + 0) * 68 + d];
        u.y = tile[(tc4 + 1) * 68 + d];
        u.z = tile[(tc4 + 2) * 68 + d];
        u.w = tile[(tc4 + 3) * 68 + d];
        *reinterpret_cast<ushort4*>(dst + (size_t)d * 2048 + tc4) = u;
    }
}

// ---------- 5) flash attention: DMA-staged K/V, XOR-swizzled LDS ----------
// KP/VT stride 128 elems (256B): bank = f(chunk) only; swizzle p = c ^ (row&7)
// applied at the *global source* of the DMA. P reuses KP (same swizzle).
__global__ __launch_bounds__(256, 2) void k_flash(const u16* __restrict__ qkv,
                                                  const u16* __restrict__ vt,
                                                  u16* __restrict__ out) {
    __shared__ __align__(16) u16 KP[128 * 128];
    __shared__ __align__(16) u16 VT[128 * 128];
    const int t = threadIdx.x, lane = t & 63, wave = t >> 6;
    const int m16 = lane & 15, qd = lane >> 4;
    const int m7 = m16 & 7;
    const int bh = blockIdx.y, b = bh >> 4, h = bh & 15;
    const int q0 = blockIdx.x * 128;
    const int wq = wave * 32;
    const u16* Qg = qkv + (size_t)b * 2048 * 6144 + (size_t)h * 128;
    const u16* Kg = Qg + 2048;
    const u16* Vtg = vt + (size_t)bh * 128 * 2048;
    const float C2 = 0.12751743f;   // (1/sqrt(128)) * log2(e)

    // DMA staging geometry: per issue, wave covers 4 rows x 16 chunks.
    const int dma_rl = lane >> 4;          // row within 4-row slab
    const int dma_pc = lane & 15;          // phys chunk this lane fills

    // Persistent Q fragments (A-layout)
    s16x8 qf[2][4];
#pragma unroll
    for (int mi = 0; mi < 2; ++mi)
#pragma unroll
        for (int kc = 0; kc < 4; ++kc)
            qf[mi][kc] = *reinterpret_cast<const s16x8*>(
                Qg + (size_t)(q0 + wq + mi * 16 + m16) * 6144 + kc * 32 + qd * 8);

    f32x4 accO[2][8] = {};
    float mrow[2][4], lrow[2][4];
#pragma unroll
    for (int mi = 0; mi < 2; ++mi)
#pragma unroll
        for (int r = 0; r < 4; ++r) { mrow[mi][r] = -1e30f; lrow[mi][r] = 0.f; }

    for (int kt = 0; kt < 16; ++kt) {
        const int s0 = kt * 128;
        __syncthreads();   // prev iter done reading KP(P)/VT
#pragma unroll
        for (int rd = 0; rd < 8; ++rd) {
            int row = rd * 16 + wave * 4 + dma_rl;
            int c = dma_pc ^ (row & 7);                     // logical chunk
            gl2lds16(Kg  + (size_t)(s0 + row) * 6144 + c * 8, &KP[(rd * 16 + wave * 4) * 128]);
            gl2lds16(Vtg + (size_t)row * 2048 + s0 + c * 8,   &VT[(rd * 16 + wave * 4) * 128]);
        }
        __syncthreads();   // vmcnt(0) drain: tiles resident

        // QK^T: kf = K[s_k=nj*16+m16][d chunks]
        f32x4 accS[2][8] = {};
#pragma unroll
        for (int kc = 0; kc < 4; ++kc)
#pragma unroll
            for (int nj = 0; nj < 8; ++nj) {
                s16x8 kf = *reinterpret_cast<const s16x8*>(
                    &KP[(nj * 16 + m16) * 128 + ((kc * 4 + qd) ^ m7) * 8]);
                accS[0][nj] = __builtin_amdgcn_mfma_f32_16x16x32_bf16(qf[0][kc], kf, accS[0][nj], 0, 0, 0);
                accS[1][nj] = __builtin_amdgcn_mfma_f32_16x16x32_bf16(qf[1][kc], kf, accS[1][nj], 0, 0, 0);
            }
        __syncthreads();   // all K reads done before P overwrites KP

        // online softmax (exp2 domain); score (row=qd*4+r, col=nj*16+m16)
        float alpha[2][4], psum[2][4];
#pragma unroll
        for (int mi = 0; mi < 2; ++mi)
#pragma unroll
            for (int r = 0; r < 4; ++r) {
                float mx = accS[mi][0][r];
#pragma unroll
                for (int nj = 1; nj < 8; ++nj) mx = fmaxf(mx, accS[mi][nj][r]);
#pragma unroll
                for (int off = 1; off < 16; off <<= 1) mx = fmaxf(mx, __shfl_xor(mx, off));
                float mn = fmaxf(mrow[mi][r], mx * C2);
                alpha[mi][r] = exp2f(mrow[mi][r] - mn);
                mrow[mi][r] = mn;
                psum[mi][r] = 0.f;
            }
#pragma unroll
        for (int mi = 0; mi < 2; ++mi)
#pragma unroll
            for (int nj = 0; nj < 8; ++nj)
#pragma unroll
                for (int r = 0; r < 4; ++r) {
                    float p = exp2f(accS[mi][nj][r] * C2 - mrow[mi][r]);
                    psum[mi][r] += p;
                    int prow = wq + mi * 16 + qd * 4 + r;
                    int pphys = (nj * 2 + (m16 >> 3)) ^ (prow & 7);
                    KP[prow * 128 + pphys * 8 + m7] = f32_to_bf16_rhu(p);
                }
#pragma unroll
        for (int mi = 0; mi < 2; ++mi)
#pragma unroll
            for (int r = 0; r < 4; ++r) {
                float sum = psum[mi][r];
#pragma unroll
                for (int off = 1; off < 16; off <<= 1) sum += __shfl_xor(sum, off);
                lrow[mi][r] = lrow[mi][r] * alpha[mi][r] + sum;
            }
#pragma unroll
        for (int mi = 0; mi < 2; ++mi)
#pragma unroll
            for (int dj = 0; dj < 8; ++dj)
#pragma unroll
                for (int r = 0; r < 4; ++r) accO[mi][dj][r] *= alpha[mi][r];

        // PV: pf = P[q=wq+mi*16+m16][s_k chunks] (own wave's rows), vf = V^T[d][s_k]
#pragma unroll
        for (int ks = 0; ks < 4; ++ks) {
            s16x8 pf0 = *reinterpret_cast<const s16x8*>(
                &KP[(wq + m16) * 128 + ((ks * 4 + qd) ^ m7) * 8]);
            s16x8 pf1 = *reinterpret_cast<const s16x8*>(
                &KP[(wq + 16 + m16) * 128 + ((ks * 4 + qd) ^ m7) * 8]);
#pragma unroll
            for (int dj = 0; dj < 8; ++dj) {
                s16x8 vf = *reinterpret_cast<const s16x8*>(
                    &VT[(dj * 16 + m16) * 128 + ((ks * 4 + qd) ^ m7) * 8]);
                accO[0][dj] = __builtin_amdgcn_mfma_f32_16x16x32_bf16(pf0, vf, accO[0][dj], 0, 0, 0);
                accO[1][dj] = __builtin_amdgcn_mfma_f32_16x16x32_bf16(pf1, vf, accO[1][dj], 0, 0, 0);
            }
        }
    }
    // epilogue
#pragma unroll
    for (int mi = 0; mi < 2; ++mi)
#pragma unroll
        for (int r = 0; r < 4; ++r) {
            float inv = 1.0f / lrow[mi][r];
            size_t row = (size_t)b * 2048 + q0 + wq + mi * 16 + qd * 4 + r;
#pragma unroll
            for (int dj = 0; dj < 8; ++dj)
                out[row * 2048 + h * 128 + dj * 16 + m16] =
                    f32_to_bf16_rne(accO[mi][dj][r] * inv);
        }
}

// ---------- launch ----------
extern "C" void kernel_launch(void* const* d_in, const int* in_sizes, int n_in,
                              void* d_out, int out_size, void* d_ws, size_t ws_size,
                              hipStream_t stream) {
    const float* x     = (const float*)d_in[0];
    const float* W_qkv = (const float*)d_in[1];
    const float* W_out = (const float*)d_in[2];
    float* out = (float*)d_out;

    char* ws = (char*)d_ws;
    u16* xb   = (u16*)(ws);
    u16* Wqt  = (u16*)(ws + (16u << 20));
    u16* Wot  = (u16*)(ws + (40u << 20));
    u16* qkvb = (u16*)(ws + (48u << 20));
    u16* attn = (u16*)(ws + (96u << 20));
    u16* vtg  = (u16*)(ws + (112u << 20));

    k_cast<<<8192, 256, 0, stream>>>(x, xb);
    k_transpose_cast<<<dim3(96, 32), 256, 0, stream>>>(W_qkv, Wqt, 2048, 6144);
    k_transpose_cast<<<dim3(32, 32), 256, 0, stream>>>(W_out, Wot, 2048, 2048);
    k_gemm_bt<true, true><<<dim3(48, 32), 256, 0, stream>>>(xb, Wqt, qkvb, 4096, 6144, 2048);
    k_transpose_v<<<dim3(32, 64), 256, 0, stream>>>(qkvb, vtg);
    k_flash<<<dim3(16, 32), 256, 0, stream>>>(qkvb, vtg, attn);
    k_gemm_bt<false, false><<<dim3(16, 32), 256, 0, stream>>>(attn, Wot, out, 4096, 2048, 2048);
}

// Round 4
// 455.081 us; speedup vs baseline: 1.4556x; 1.4556x over previous
//
#include <hip/hip_runtime.h>
#include <math.h>

typedef float  f32x4 __attribute__((ext_vector_type(4)));
typedef short  s16x8 __attribute__((ext_vector_type(8)));
typedef short  s16x4 __attribute__((ext_vector_type(4)));
typedef unsigned short u16;
typedef unsigned int u32;

// ---------- bf16 helpers ----------
static __device__ __forceinline__ u16 f32_to_bf16_rne(float f) {
    u32 u = __builtin_bit_cast(u32, f);
    u32 r = u + 0x7fffu + ((u >> 16) & 1u);
    return (u16)(r >> 16);
}
static __device__ __forceinline__ u16 f32_to_bf16_rhu(float f) {
    u32 u = __builtin_bit_cast(u32, f);
    return (u16)((u + 0x8000u) >> 16);
}
static __device__ __forceinline__ float bf16_to_f32(u16 h) {
    return __builtin_bit_cast(float, (u32)h << 16);
}

// async global->LDS 16B (lane-contiguous source ONLY — R3 lesson)
static __device__ __forceinline__ void gl2lds16(const void* g, void* l) {
    __builtin_amdgcn_global_load_lds(
        (const __attribute__((address_space(1))) u32*)g,
        (__attribute__((address_space(3))) u32*)l, 16, 0, 0);
}

// ---------- 1) cast fp32 -> bf16 ----------
__global__ void k_cast(const float* __restrict__ in, u16* __restrict__ out) {
    int i = (blockIdx.x * 256 + threadIdx.x) * 4;
    float4 v = *reinterpret_cast<const float4*>(in + i);
    ushort4 u;
    u.x = f32_to_bf16_rne(v.x); u.y = f32_to_bf16_rne(v.y);
    u.z = f32_to_bf16_rne(v.z); u.w = f32_to_bf16_rne(v.w);
    *reinterpret_cast<ushort4*>(out + i) = u;
}

// ---------- 2) transpose + cast: W (R x C fp32) -> Wt (C x R bf16) ----------
__global__ void k_transpose_cast(const float* __restrict__ in, u16* __restrict__ out,
                                 int R, int C) {
    __shared__ __align__(16) float tile[64 * 68];
    const int ct = blockIdx.x, rt = blockIdx.y;
    const int t = threadIdx.x;
    const int tr = t >> 4;
    const int tc4 = (t & 15) * 4;
#pragma unroll
    for (int rn = 0; rn < 4; ++rn) {
        int r = rn * 16 + tr;
        float4 v = *reinterpret_cast<const float4*>(in + (size_t)(rt * 64 + r) * C + ct * 64 + tc4);
        *reinterpret_cast<float4*>(&tile[r * 68 + tc4]) = v;
    }
    __syncthreads();
#pragma unroll
    for (int rn = 0; rn < 4; ++rn) {
        int oc = rn * 16 + tr;
        ushort4 u;
        u.x = f32_to_bf16_rne(tile[(tc4 + 0) * 68 + oc]);
        u.y = f32_to_bf16_rne(tile[(tc4 + 1) * 68 + oc]);
        u.z = f32_to_bf16_rne(tile[(tc4 + 2) * 68 + oc]);
        u.w = f32_to_bf16_rne(tile[(tc4 + 3) * 68 + oc]);
        *reinterpret_cast<ushort4*>(out + (size_t)(ct * 64 + oc) * R + rt * 64 + tc4) = u;
    }
}

// ---------- 3) GEMM m97-style (unchanged from R3 — measured OK) ----------
template<bool BF16OUT, bool ROPE>
__global__ __launch_bounds__(256) void k_gemm_bt(const u16* __restrict__ Amat,
                                                 const u16* __restrict__ Bt,
                                                 void* __restrict__ Cout,
                                                 int M, int N, int K) {
    __shared__ __align__(16) u16 As[128 * 64];
    __shared__ __align__(16) u16 Bs[128 * 64];
    const int t = threadIdx.x;
    const int lane = t & 63, wave = t >> 6;
    const int m16 = lane & 15, qd = lane >> 4;
    const int wm = (wave >> 1) * 64, wn = (wave & 1) * 64;
    const size_t m0 = (size_t)blockIdx.y * 128, n0 = (size_t)blockIdx.x * 128;
    const int srow = lane >> 3;
    const int schunk = (lane & 7) ^ srow;

    f32x4 acc[4][4] = {};

    for (int k0 = 0; k0 < K; k0 += 64) {
#pragma unroll
        for (int j = 0; j < 4; ++j) {
            int rbase = j * 32 + wave * 8;
            int r = rbase + srow;
            gl2lds16(Amat + (m0 + r) * (size_t)K + k0 + schunk * 8, &As[rbase * 64]);
            gl2lds16(Bt   + (n0 + r) * (size_t)K + k0 + schunk * 8, &Bs[rbase * 64]);
        }
        __syncthreads();
#pragma unroll
        for (int kh = 0; kh < 2; ++kh) {
            s16x8 af[4], bf[4];
#pragma unroll
            for (int i = 0; i < 4; ++i) {
                int ra = wm + i * 16 + m16;
                int pa = (kh * 4 + qd) ^ (ra & 7);
                af[i] = *reinterpret_cast<const s16x8*>(&As[ra * 64 + pa * 8]);
                int rb = wn + i * 16 + m16;
                int pb = (kh * 4 + qd) ^ (rb & 7);
                bf[i] = *reinterpret_cast<const s16x8*>(&Bs[rb * 64 + pb * 8]);
            }
#pragma unroll
            for (int i = 0; i < 4; ++i)
#pragma unroll
                for (int jj = 0; jj < 4; ++jj)
                    acc[i][jj] = __builtin_amdgcn_mfma_f32_16x16x32_bf16(af[i], bf[jj], acc[i][jj], 0, 0, 0);
        }
        __syncthreads();
    }
    if (ROPE && n0 < 4096) {
        float invf[4];
#pragma unroll
        for (int j = 0; j < 4; ++j) {
            int pi = ((int)(wn + j * 16 + m16) & 127) >> 1;
            invf[j] = __expf(-0.14391156831f * (float)pi);
        }
#pragma unroll
        for (int i = 0; i < 4; ++i)
#pragma unroll
            for (int j = 0; j < 4; ++j)
#pragma unroll
                for (int r = 0; r < 4; ++r) {
                    float v = acc[i][j][r];
                    float p = __shfl_xor(v, 1);
                    size_t row = m0 + wm + i * 16 + qd * 4 + r;
                    float f = (float)(int)(row & 2047) * invf[j];
                    float sn, cs;
                    __sincosf(f, &sn, &cs);
                    float res = (m16 & 1) ? fmaf(p, sn, v * cs) : fmaf(v, cs, -p * sn);
                    size_t col = n0 + wn + j * 16 + m16;
                    ((u16*)Cout)[row * N + col] = f32_to_bf16_rne(res);
                }
    } else {
#pragma unroll
        for (int i = 0; i < 4; ++i)
#pragma unroll
            for (int j = 0; j < 4; ++j)
#pragma unroll
                for (int r = 0; r < 4; ++r) {
                    size_t row = m0 + wm + i * 16 + qd * 4 + r;
                    size_t col = n0 + wn + j * 16 + m16;
                    if (BF16OUT)
                        ((u16*)Cout)[row * N + col] = f32_to_bf16_rne(acc[i][j][r]);
                    else
                        ((float*)Cout)[row * N + col] = acc[i][j][r];
                }
    }
}

// ---------- 4) V -> V^T ----------
__global__ void k_transpose_v(const u16* __restrict__ qkv, u16* __restrict__ vt) {
    __shared__ u16 tile[64 * 68];
    const int st = blockIdx.x;
    const int bhd = blockIdx.y;
    const int bh = bhd >> 1, dt = bhd & 1;
    const u16* src = qkv + (size_t)(bh >> 4) * 2048 * 6144 + 4096 + (size_t)(bh & 15) * 128 + dt * 64;
    const int t = threadIdx.x, tr = t >> 4, tc4 = (t & 15) * 4;
#pragma unroll
    for (int rn = 0; rn < 4; ++rn) {
        int s = rn * 16 + tr;
        *reinterpret_cast<ushort4*>(&tile[s * 68 + tc4]) =
            *reinterpret_cast<const ushort4*>(src + (size_t)(st * 64 + s) * 6144 + tc4);
    }
    __syncthreads();
    u16* dst = vt + ((size_t)bh * 128 + dt * 64) * 2048 + st * 64;
#pragma unroll
    for (int rn = 0; rn < 4; ++rn) {
        int d = rn * 16 + tr;
        ushort4 u;
        u.x = tile[(tc4 + 0) * 68 + d];
        u.y = tile[(tc4 + 1) * 68 + d];
        u.z = tile[(tc4 + 2) * 68 + d];
        u.w = tile[(tc4 + 3) * 68 + d];
        *reinterpret_cast<ushort4*>(dst + (size_t)d * 2048 + tc4) = u;
    }
}

// ---------- 5) flash attention, S^T formulation: P never touches LDS ----------
// S^T = K·Q^T gives lane q=lane&15, s_k = nj*16+qd*4+r. PV uses a k-permutation
// sigma(k=qd*8+j) = (2kb+(j>>2))*16 + qd*4 + (j&3), applied to BOTH operands:
// A-frag (P) is lane-local packed exps; B-frag (V) = two ds_read_b64 from V^T.
// LDS stride 136: staging writes, kf b128, vf b64 all bank-uniform.
__global__ __launch_bounds__(256, 2) void k_flash(const u16* __restrict__ qkv,
                                                  const u16* __restrict__ vt,
                                                  u16* __restrict__ out) {
    __shared__ __align__(16) u16 KS[128 * 136];
    __shared__ __align__(16) u16 VS[128 * 136];
    const int t = threadIdx.x, lane = t & 63, wave = t >> 6;
    const int m16 = lane & 15, qd = lane >> 4;
    const int bh = blockIdx.y, b = bh >> 4, h = bh & 15;
    const int q0 = blockIdx.x * 128;
    const int wq = wave * 32;
    const u16* Qg = qkv + (size_t)b * 2048 * 6144 + (size_t)h * 128;
    const u16* Kg = Qg + 2048;
    const u16* Vtg = vt + (size_t)bh * 128 * 2048;
    const float C2 = 0.12751743f;   // (1/sqrt(128)) * log2(e)

    // Persistent Q fragments (B-operand of S^T; same frag structure as A)
    s16x8 qf[2][4];
#pragma unroll
    for (int mi = 0; mi < 2; ++mi)
#pragma unroll
        for (int kc = 0; kc < 4; ++kc)
            qf[mi][kc] = *reinterpret_cast<const s16x8*>(
                Qg + (size_t)(q0 + wq + mi * 16 + m16) * 6144 + kc * 32 + qd * 8);

    f32x4 accO[2][8] = {};
    float mrow[2] = {-1e30f, -1e30f};   // per-lane state for q = m16 (per mi)
    float lrow[2] = {0.f, 0.f};

    const int strow = t >> 4;        // 0..15
    const int stc = (t & 15) * 8;    // 0..120

    for (int kt = 0; kt < 16; ++kt) {
        const int s0 = kt * 128;
        __syncthreads();   // prev iter's KS/VS reads complete
#pragma unroll
        for (int rd = 0; rd < 8; ++rd) {
            int row = rd * 16 + strow;
            *reinterpret_cast<s16x8*>(&KS[row * 136 + stc]) =
                *reinterpret_cast<const s16x8*>(Kg + (size_t)(s0 + row) * 6144 + stc);
            *reinterpret_cast<s16x8*>(&VS[row * 136 + stc]) =
                *reinterpret_cast<const s16x8*>(Vtg + (size_t)row * 2048 + s0 + stc);
        }
        __syncthreads();

        // S^T = K·Q^T : A = kf (m = s_k), B = qf (n = q)
        f32x4 accS[2][8] = {};
#pragma unroll
        for (int kc = 0; kc < 4; ++kc)
#pragma unroll
            for (int nj = 0; nj < 8; ++nj) {
                s16x8 kf = *reinterpret_cast<const s16x8*>(
                    &KS[(nj * 16 + m16) * 136 + (kc * 4 + qd) * 8]);
                accS[0][nj] = __builtin_amdgcn_mfma_f32_16x16x32_bf16(kf, qf[0][kc], accS[0][nj], 0, 0, 0);
                accS[1][nj] = __builtin_amdgcn_mfma_f32_16x16x32_bf16(kf, qf[1][kc], accS[1][nj], 0, 0, 0);
            }

        // online softmax, per-lane column q = m16; pack P lane-locally
        s16x4 pk[2][8];
        float aO[2][4];
#pragma unroll
        for (int mi = 0; mi < 2; ++mi) {
            float mx = accS[mi][0][0];
#pragma unroll
            for (int nj = 0; nj < 8; ++nj)
#pragma unroll
                for (int r = 0; r < 4; ++r) mx = fmaxf(mx, accS[mi][nj][r]);
            mx *= C2;
            mx = fmaxf(mx, __shfl_xor(mx, 16));
            mx = fmaxf(mx, __shfl_xor(mx, 32));
            float mn = fmaxf(mrow[mi], mx);
            float alpha = exp2f(mrow[mi] - mn);
            mrow[mi] = mn;
            float ls = 0.f;
#pragma unroll
            for (int nj = 0; nj < 8; ++nj) {
                float p0 = exp2f(accS[mi][nj][0] * C2 - mn);
                float p1 = exp2f(accS[mi][nj][1] * C2 - mn);
                float p2 = exp2f(accS[mi][nj][2] * C2 - mn);
                float p3 = exp2f(accS[mi][nj][3] * C2 - mn);
                ls += (p0 + p1) + (p2 + p3);
                s16x4 pv;
                pv[0] = (short)f32_to_bf16_rhu(p0);
                pv[1] = (short)f32_to_bf16_rhu(p1);
                pv[2] = (short)f32_to_bf16_rhu(p2);
                pv[3] = (short)f32_to_bf16_rhu(p3);
                pk[mi][nj] = pv;
            }
            ls += __shfl_xor(ls, 16);
            ls += __shfl_xor(ls, 32);
            lrow[mi] = lrow[mi] * alpha + ls;
#pragma unroll
            for (int r = 0; r < 4; ++r)
                aO[mi][r] = __shfl(alpha, qd * 4 + r);   // alpha for q = qd*4+r
#pragma unroll
            for (int dj = 0; dj < 8; ++dj)
#pragma unroll
                for (int r = 0; r < 4; ++r) accO[mi][dj][r] *= aO[mi][r];
        }

        // PV with k-permutation sigma: A lane-local, B = 2x b64 from VS
#pragma unroll
        for (int kb = 0; kb < 4; ++kb) {
            s16x8 af0 = __builtin_shufflevector(pk[0][2 * kb], pk[0][2 * kb + 1],
                                                0, 1, 2, 3, 4, 5, 6, 7);
            s16x8 af1 = __builtin_shufflevector(pk[1][2 * kb], pk[1][2 * kb + 1],
                                                0, 1, 2, 3, 4, 5, 6, 7);
#pragma unroll
            for (int dj = 0; dj < 8; ++dj) {
                const u16* vrow = &VS[(dj * 16 + m16) * 136 + kb * 32 + qd * 4];
                s16x4 lo = *reinterpret_cast<const s16x4*>(vrow);
                s16x4 hi = *reinterpret_cast<const s16x4*>(vrow + 16);
                s16x8 vf = __builtin_shufflevector(lo, hi, 0, 1, 2, 3, 4, 5, 6, 7);
                accO[0][dj] = __builtin_amdgcn_mfma_f32_16x16x32_bf16(af0, vf, accO[0][dj], 0, 0, 0);
                accO[1][dj] = __builtin_amdgcn_mfma_f32_16x16x32_bf16(af1, vf, accO[1][dj], 0, 0, 0);
            }
        }
    }
    // epilogue: O rows q = qd*4+r, cols d = dj*16+m16
#pragma unroll
    for (int mi = 0; mi < 2; ++mi) {
        float invl = 1.0f / lrow[mi];
        float iv[4];
#pragma unroll
        for (int r = 0; r < 4; ++r) iv[r] = __shfl(invl, qd * 4 + r);
#pragma unroll
        for (int r = 0; r < 4; ++r) {
            size_t row = (size_t)b * 2048 + q0 + wq + mi * 16 + qd * 4 + r;
#pragma unroll
            for (int dj = 0; dj < 8; ++dj)
                out[row * 2048 + h * 128 + dj * 16 + m16] =
                    f32_to_bf16_rne(accO[mi][dj][r] * iv[r]);
        }
    }
}

// ---------- launch ----------
extern "C" void kernel_launch(void* const* d_in, const int* in_sizes, int n_in,
                              void* d_out, int out_size, void* d_ws, size_t ws_size,
                              hipStream_t stream) {
    const float* x     = (const float*)d_in[0];
    const float* W_qkv = (const float*)d_in[1];
    const float* W_out = (const float*)d_in[2];
    float* out = (float*)d_out;

    char* ws = (char*)d_ws;
    u16* xb   = (u16*)(ws);
    u16* Wqt  = (u16*)(ws + (16u << 20));
    u16* Wot  = (u16*)(ws + (40u << 20));
    u16* qkvb = (u16*)(ws + (48u << 20));
    u16* attn = (u16*)(ws + (96u << 20));
    u16* vtg  = (u16*)(ws + (112u << 20));

    k_cast<<<8192, 256, 0, stream>>>(x, xb);
    k_transpose_cast<<<dim3(96, 32), 256, 0, stream>>>(W_qkv, Wqt, 2048, 6144);
    k_transpose_cast<<<dim3(32, 32), 256, 0, stream>>>(W_out, Wot, 2048, 2048);
    k_gemm_bt<true, true><<<dim3(48, 32), 256, 0, stream>>>(xb, Wqt, qkvb, 4096, 6144, 2048);
    k_transpose_v<<<dim3(32, 64), 256, 0, stream>>>(qkvb, vtg);
    k_flash<<<dim3(16, 32), 256, 0, stream>>>(qkvb, vtg, attn);
    k_gemm_bt<false, false><<<dim3(16, 32), 256, 0, stream>>>(attn, Wot, out, 4096, 2048, 2048);
}

// Round 5
// 411.699 us; speedup vs baseline: 1.6090x; 1.1054x over previous
//
#include <hip/hip_runtime.h>
#include <math.h>

typedef float  f32x4 __attribute__((ext_vector_type(4)));
typedef short  s16x8 __attribute__((ext_vector_type(8)));
typedef short  s16x4 __attribute__((ext_vector_type(4)));
typedef unsigned short u16;
typedef unsigned int u32;

// ---------- bf16 helpers ----------
static __device__ __forceinline__ u16 f32_to_bf16_rne(float f) {
    u32 u = __builtin_bit_cast(u32, f);
    u32 r = u + 0x7fffu + ((u >> 16) & 1u);
    return (u16)(r >> 16);
}
static __device__ __forceinline__ u32 pack_bf16_rhu(float a, float b) {
    u32 ua = __builtin_bit_cast(u32, a);
    u32 ub = __builtin_bit_cast(u32, b);
    return ((ua + 0x8000u) >> 16) | ((ub + 0x8000u) & 0xffff0000u);
}
static __device__ __forceinline__ float bf16_to_f32(u16 h) {
    return __builtin_bit_cast(float, (u32)h << 16);
}

// async global->LDS 16B (lane-contiguous source ONLY — R3 lesson)
static __device__ __forceinline__ void gl2lds16(const void* g, void* l) {
    __builtin_amdgcn_global_load_lds(
        (const __attribute__((address_space(1))) u32*)g,
        (__attribute__((address_space(3))) u32*)l, 16, 0, 0);
}

// ---------- 1) cast fp32 -> bf16 ----------
__global__ void k_cast(const float* __restrict__ in, u16* __restrict__ out) {
    int i = (blockIdx.x * 256 + threadIdx.x) * 4;
    float4 v = *reinterpret_cast<const float4*>(in + i);
    ushort4 u;
    u.x = f32_to_bf16_rne(v.x); u.y = f32_to_bf16_rne(v.y);
    u.z = f32_to_bf16_rne(v.z); u.w = f32_to_bf16_rne(v.w);
    *reinterpret_cast<ushort4*>(out + i) = u;
}

// ---------- 2) transpose + cast: W (R x C fp32) -> Wt (C x R bf16) ----------
__global__ void k_transpose_cast(const float* __restrict__ in, u16* __restrict__ out,
                                 int R, int C) {
    __shared__ __align__(16) float tile[64 * 68];
    const int ct = blockIdx.x, rt = blockIdx.y;
    const int t = threadIdx.x;
    const int tr = t >> 4;
    const int tc4 = (t & 15) * 4;
#pragma unroll
    for (int rn = 0; rn < 4; ++rn) {
        int r = rn * 16 + tr;
        float4 v = *reinterpret_cast<const float4*>(in + (size_t)(rt * 64 + r) * C + ct * 64 + tc4);
        *reinterpret_cast<float4*>(&tile[r * 68 + tc4]) = v;
    }
    __syncthreads();
#pragma unroll
    for (int rn = 0; rn < 4; ++rn) {
        int oc = rn * 16 + tr;
        ushort4 u;
        u.x = f32_to_bf16_rne(tile[(tc4 + 0) * 68 + oc]);
        u.y = f32_to_bf16_rne(tile[(tc4 + 1) * 68 + oc]);
        u.z = f32_to_bf16_rne(tile[(tc4 + 2) * 68 + oc]);
        u.w = f32_to_bf16_rne(tile[(tc4 + 3) * 68 + oc]);
        *reinterpret_cast<ushort4*>(out + (size_t)(ct * 64 + oc) * R + rt * 64 + tc4) = u;
    }
}

// ---------- 3) GEMM m97-style (unchanged — measured OK) ----------
template<bool BF16OUT, bool ROPE>
__global__ __launch_bounds__(256) void k_gemm_bt(const u16* __restrict__ Amat,
                                                 const u16* __restrict__ Bt,
                                                 void* __restrict__ Cout,
                                                 int M, int N, int K) {
    __shared__ __align__(16) u16 As[128 * 64];
    __shared__ __align__(16) u16 Bs[128 * 64];
    const int t = threadIdx.x;
    const int lane = t & 63, wave = t >> 6;
    const int m16 = lane & 15, qd = lane >> 4;
    const int wm = (wave >> 1) * 64, wn = (wave & 1) * 64;
    const size_t m0 = (size_t)blockIdx.y * 128, n0 = (size_t)blockIdx.x * 128;
    const int srow = lane >> 3;
    const int schunk = (lane & 7) ^ srow;

    f32x4 acc[4][4] = {};

    for (int k0 = 0; k0 < K; k0 += 64) {
#pragma unroll
        for (int j = 0; j < 4; ++j) {
            int rbase = j * 32 + wave * 8;
            int r = rbase + srow;
            gl2lds16(Amat + (m0 + r) * (size_t)K + k0 + schunk * 8, &As[rbase * 64]);
            gl2lds16(Bt   + (n0 + r) * (size_t)K + k0 + schunk * 8, &Bs[rbase * 64]);
        }
        __syncthreads();
#pragma unroll
        for (int kh = 0; kh < 2; ++kh) {
            s16x8 af[4], bf[4];
#pragma unroll
            for (int i = 0; i < 4; ++i) {
                int ra = wm + i * 16 + m16;
                int pa = (kh * 4 + qd) ^ (ra & 7);
                af[i] = *reinterpret_cast<const s16x8*>(&As[ra * 64 + pa * 8]);
                int rb = wn + i * 16 + m16;
                int pb = (kh * 4 + qd) ^ (rb & 7);
                bf[i] = *reinterpret_cast<const s16x8*>(&Bs[rb * 64 + pb * 8]);
            }
#pragma unroll
            for (int i = 0; i < 4; ++i)
#pragma unroll
                for (int jj = 0; jj < 4; ++jj)
                    acc[i][jj] = __builtin_amdgcn_mfma_f32_16x16x32_bf16(af[i], bf[jj], acc[i][jj], 0, 0, 0);
        }
        __syncthreads();
    }
    if (ROPE && n0 < 4096) {
        float invf[4];
#pragma unroll
        for (int j = 0; j < 4; ++j) {
            int pi = ((int)(wn + j * 16 + m16) & 127) >> 1;
            invf[j] = __expf(-0.14391156831f * (float)pi);
        }
#pragma unroll
        for (int i = 0; i < 4; ++i)
#pragma unroll
            for (int j = 0; j < 4; ++j)
#pragma unroll
                for (int r = 0; r < 4; ++r) {
                    float v = acc[i][j][r];
                    float p = __shfl_xor(v, 1);
                    size_t row = m0 + wm + i * 16 + qd * 4 + r;
                    float f = (float)(int)(row & 2047) * invf[j];
                    float sn, cs;
                    __sincosf(f, &sn, &cs);
                    float res = (m16 & 1) ? fmaf(p, sn, v * cs) : fmaf(v, cs, -p * sn);
                    size_t col = n0 + wn + j * 16 + m16;
                    ((u16*)Cout)[row * N + col] = f32_to_bf16_rne(res);
                }
    } else {
#pragma unroll
        for (int i = 0; i < 4; ++i)
#pragma unroll
            for (int j = 0; j < 4; ++j)
#pragma unroll
                for (int r = 0; r < 4; ++r) {
                    size_t row = m0 + wm + i * 16 + qd * 4 + r;
                    size_t col = n0 + wn + j * 16 + m16;
                    if (BF16OUT)
                        ((u16*)Cout)[row * N + col] = f32_to_bf16_rne(acc[i][j][r]);
                    else
                        ((float*)Cout)[row * N + col] = acc[i][j][r];
                }
    }
}

// ---------- 4) V -> V^T ----------
__global__ void k_transpose_v(const u16* __restrict__ qkv, u16* __restrict__ vt) {
    __shared__ u16 tile[64 * 68];
    const int st = blockIdx.x;
    const int bhd = blockIdx.y;
    const int bh = bhd >> 1, dt = bhd & 1;
    const u16* src = qkv + (size_t)(bh >> 4) * 2048 * 6144 + 4096 + (size_t)(bh & 15) * 128 + dt * 64;
    const int t = threadIdx.x, tr = t >> 4, tc4 = (t & 15) * 4;
#pragma unroll
    for (int rn = 0; rn < 4; ++rn) {
        int s = rn * 16 + tr;
        *reinterpret_cast<ushort4*>(&tile[s * 68 + tc4]) =
            *reinterpret_cast<const ushort4*>(src + (size_t)(st * 64 + s) * 6144 + tc4);
    }
    __syncthreads();
    u16* dst = vt + ((size_t)bh * 128 + dt * 64) * 2048 + st * 64;
#pragma unroll
    for (int rn = 0; rn < 4; ++rn) {
        int d = rn * 16 + tr;
        ushort4 u;
        u.x = tile[(tc4 + 0) * 68 + d];
        u.y = tile[(tc4 + 1) * 68 + d];
        u.z = tile[(tc4 + 2) * 68 + d];
        u.w = tile[(tc4 + 3) * 68 + d];
        *reinterpret_cast<ushort4*>(dst + (size_t)d * 2048 + tc4) = u;
    }
}

// ---------- 5) flash attention: 512 threads (8 waves), S^T form, pi-layout V ----------
// Each wave owns 16 q rows. KS plain [s_k][d] stride 136. VS pi-permuted:
// column s = 32kb+16t+4qd+r stored at pi(s) = 32kb+8qd+4t+r, so the PV B-frag
// is ONE ds_read_b128 at VS[d*136 + 32kb + 8qd]. All b128 phases spread 8
// lanes/quad (conflict-free); V staging b64 writes ~2 lanes/bank.
__global__ __launch_bounds__(512, 4) void k_flash(const u16* __restrict__ qkv,
                                                  const u16* __restrict__ vt,
                                                  u16* __restrict__ out) {
    __shared__ __align__(16) u16 KS[128 * 136];
    __shared__ __align__(16) u16 VS[128 * 136];
    const int t = threadIdx.x, lane = t & 63, wave = t >> 6;
    const int m16 = lane & 15, qd = lane >> 4;
    const int bh = blockIdx.y, b = bh >> 4, h = bh & 15;
    const int q0 = blockIdx.x * 128;
    const u16* Qg = qkv + (size_t)b * 2048 * 6144 + (size_t)h * 128;
    const u16* Kg = Qg + 2048;
    const u16* Vtg = vt + (size_t)bh * 128 * 2048;
    const float C2 = 0.12751743f;   // (1/sqrt(128)) * log2(e)

    // Staging geometry (4 chunks each of K and V per thread), loop-invariant
    int srow[4], scol[4], pi0[4];
#pragma unroll
    for (int ci = 0; ci < 4; ++ci) {
        int idx = ci * 512 + t;
        int row = idx >> 4, c = idx & 15;
        srow[ci] = row;
        scol[ci] = c * 8;
        pi0[ci] = 32 * (c >> 2) + 16 * (c & 1) + 4 * ((c >> 1) & 1);
    }

    // Persistent Q fragments: q = q0 + wave*16 + m16
    s16x8 qf[4];
#pragma unroll
    for (int kc = 0; kc < 4; ++kc)
        qf[kc] = *reinterpret_cast<const s16x8*>(
            Qg + (size_t)(q0 + wave * 16 + m16) * 6144 + kc * 32 + qd * 8);

    f32x4 accO[8] = {};
    float mrow = -1e30f, lrow = 0.f;   // per-lane state for q = m16

    for (int kt = 0; kt < 16; ++kt) {
        const int s0 = kt * 128;
        // issue global loads before the barrier (no LDS touch yet)
        s16x8 kreg[4], vreg[4];
#pragma unroll
        for (int ci = 0; ci < 4; ++ci) {
            kreg[ci] = *reinterpret_cast<const s16x8*>(
                Kg + (size_t)(s0 + srow[ci]) * 6144 + scol[ci]);
            vreg[ci] = *reinterpret_cast<const s16x8*>(
                Vtg + (size_t)srow[ci] * 2048 + s0 + scol[ci]);
        }
        __syncthreads();   // prev iter's KS/VS reads complete
#pragma unroll
        for (int ci = 0; ci < 4; ++ci) {
            *reinterpret_cast<s16x8*>(&KS[srow[ci] * 136 + scol[ci]]) = kreg[ci];
            s16x4 lo = __builtin_shufflevector(vreg[ci], vreg[ci], 0, 1, 2, 3);
            s16x4 hi = __builtin_shufflevector(vreg[ci], vreg[ci], 4, 5, 6, 7);
            *reinterpret_cast<s16x4*>(&VS[srow[ci] * 136 + pi0[ci]]) = lo;
            *reinterpret_cast<s16x4*>(&VS[srow[ci] * 136 + pi0[ci] + 8]) = hi;
        }
        __syncthreads();   // tiles resident

        // S^T = K·Q^T : lane holds S^T[s_k = nj*16+qd*4+r][q = m16]
        f32x4 accS[8] = {};
#pragma unroll
        for (int kc = 0; kc < 4; ++kc)
#pragma unroll
            for (int nj = 0; nj < 8; ++nj) {
                s16x8 kf = *reinterpret_cast<const s16x8*>(
                    &KS[(nj * 16 + m16) * 136 + (kc * 4 + qd) * 8]);
                accS[nj] = __builtin_amdgcn_mfma_f32_16x16x32_bf16(kf, qf[kc], accS[nj], 0, 0, 0);
            }

        // online softmax (exp2 domain), per-lane q = m16
        float mx = accS[0][0];
#pragma unroll
        for (int nj = 0; nj < 8; ++nj)
#pragma unroll
            for (int r = 0; r < 4; ++r) mx = fmaxf(mx, accS[nj][r]);
        mx *= C2;
        mx = fmaxf(mx, __shfl_xor(mx, 16));
        mx = fmaxf(mx, __shfl_xor(mx, 32));
        float mn = fmaxf(mrow, mx);
        float alpha = __builtin_amdgcn_exp2f(mrow - mn);
        mrow = mn;
        float ls = 0.f;
        s16x4 pk[8];
#pragma unroll
        for (int nj = 0; nj < 8; ++nj) {
            float p0 = __builtin_amdgcn_exp2f(fmaf(accS[nj][0], C2, -mn));
            float p1 = __builtin_amdgcn_exp2f(fmaf(accS[nj][1], C2, -mn));
            float p2 = __builtin_amdgcn_exp2f(fmaf(accS[nj][2], C2, -mn));
            float p3 = __builtin_amdgcn_exp2f(fmaf(accS[nj][3], C2, -mn));
            ls += (p0 + p1) + (p2 + p3);
            u32 lo = pack_bf16_rhu(p0, p1);
            u32 hi = pack_bf16_rhu(p2, p3);
            uint2 pr = make_uint2(lo, hi);
            pk[nj] = __builtin_bit_cast(s16x4, pr);
        }
        ls += __shfl_xor(ls, 16);
        ls += __shfl_xor(ls, 32);
        lrow = lrow * alpha + ls;
        float aO[4];
#pragma unroll
        for (int r = 0; r < 4; ++r) aO[r] = __shfl(alpha, qd * 4 + r);
#pragma unroll
        for (int dj = 0; dj < 8; ++dj)
#pragma unroll
            for (int r = 0; r < 4; ++r) accO[dj][r] *= aO[r];

        // PV: A = pk (lane-local, sigma-permuted k), B = single b128 from VS
#pragma unroll
        for (int kb = 0; kb < 4; ++kb) {
            s16x8 af = __builtin_shufflevector(pk[2 * kb], pk[2 * kb + 1],
                                               0, 1, 2, 3, 4, 5, 6, 7);
#pragma unroll
            for (int dj = 0; dj < 8; ++dj) {
                s16x8 vf = *reinterpret_cast<const s16x8*>(
                    &VS[(dj * 16 + m16) * 136 + kb * 32 + qd * 8]);
                accO[dj] = __builtin_amdgcn_mfma_f32_16x16x32_bf16(af, vf, accO[dj], 0, 0, 0);
            }
        }
    }
    // epilogue: O rows q = wave*16 + qd*4 + r, cols d = dj*16+m16
    float invl = 1.0f / lrow;
    float iv[4];
#pragma unroll
    for (int r = 0; r < 4; ++r) iv[r] = __shfl(invl, qd * 4 + r);
#pragma unroll
    for (int r = 0; r < 4; ++r) {
        size_t row = (size_t)b * 2048 + q0 + wave * 16 + qd * 4 + r;
#pragma unroll
        for (int dj = 0; dj < 8; ++dj)
            out[row * 2048 + h * 128 + dj * 16 + m16] =
                f32_to_bf16_rne(accO[dj][r] * iv[r]);
    }
}

// ---------- launch ----------
extern "C" void kernel_launch(void* const* d_in, const int* in_sizes, int n_in,
                              void* d_out, int out_size, void* d_ws, size_t ws_size,
                              hipStream_t stream) {
    const float* x     = (const float*)d_in[0];
    const float* W_qkv = (const float*)d_in[1];
    const float* W_out = (const float*)d_in[2];
    float* out = (float*)d_out;

    char* ws = (char*)d_ws;
    u16* xb   = (u16*)(ws);
    u16* Wqt  = (u16*)(ws + (16u << 20));
    u16* Wot  = (u16*)(ws + (40u << 20));
    u16* qkvb = (u16*)(ws + (48u << 20));
    u16* attn = (u16*)(ws + (96u << 20));
    u16* vtg  = (u16*)(ws + (112u << 20));

    k_cast<<<8192, 256, 0, stream>>>(x, xb);
    k_transpose_cast<<<dim3(96, 32), 256, 0, stream>>>(W_qkv, Wqt, 2048, 6144);
    k_transpose_cast<<<dim3(32, 32), 256, 0, stream>>>(W_out, Wot, 2048, 2048);
    k_gemm_bt<true, true><<<dim3(48, 32), 256, 0, stream>>>(xb, Wqt, qkvb, 4096, 6144, 2048);
    k_transpose_v<<<dim3(32, 64), 256, 0, stream>>>(qkvb, vtg);
    k_flash<<<dim3(16, 32), 512, 0, stream>>>(qkvb, vtg, attn);
    k_gemm_bt<false, false><<<dim3(16, 32), 256, 0, stream>>>(attn, Wot, out, 4096, 2048, 2048);
}

// Round 6
// 409.919 us; speedup vs baseline: 1.6160x; 1.0043x over previous
//
#include <hip/hip_runtime.h>
#include <math.h>

typedef float  f32x4 __attribute__((ext_vector_type(4)));
typedef short  s16x8 __attribute__((ext_vector_type(8)));
typedef short  s16x4 __attribute__((ext_vector_type(4)));
typedef unsigned short u16;
typedef unsigned int u32;

// ---------- bf16 helpers ----------
static __device__ __forceinline__ u16 f32_to_bf16_rne(float f) {
    u32 u = __builtin_bit_cast(u32, f);
    u32 r = u + 0x7fffu + ((u >> 16) & 1u);
    return (u16)(r >> 16);
}
static __device__ __forceinline__ u32 pack_bf16_rhu(float a, float b) {
    u32 ua = __builtin_bit_cast(u32, a);
    u32 ub = __builtin_bit_cast(u32, b);
    return ((ua + 0x8000u) >> 16) | ((ub + 0x8000u) & 0xffff0000u);
}
static __device__ __forceinline__ float bf16_to_f32(u16 h) {
    return __builtin_bit_cast(float, (u32)h << 16);
}

// async global->LDS 16B (lane-contiguous source ONLY — R3 lesson)
static __device__ __forceinline__ void gl2lds16(const void* g, void* l) {
    __builtin_amdgcn_global_load_lds(
        (const __attribute__((address_space(1))) u32*)g,
        (__attribute__((address_space(3))) u32*)l, 16, 0, 0);
}

// ---------- 1) cast fp32 -> bf16 (8 elems/thread, 16B stores) ----------
__global__ __launch_bounds__(256) void k_cast(const float* __restrict__ in,
                                              u16* __restrict__ out) {
    int i = (blockIdx.x * 256 + threadIdx.x) * 8;
    float4 a = *reinterpret_cast<const float4*>(in + i);
    float4 b = *reinterpret_cast<const float4*>(in + i + 4);
    s16x8 o;
    o[0] = (short)f32_to_bf16_rne(a.x); o[1] = (short)f32_to_bf16_rne(a.y);
    o[2] = (short)f32_to_bf16_rne(a.z); o[3] = (short)f32_to_bf16_rne(a.w);
    o[4] = (short)f32_to_bf16_rne(b.x); o[5] = (short)f32_to_bf16_rne(b.y);
    o[6] = (short)f32_to_bf16_rne(b.z); o[7] = (short)f32_to_bf16_rne(b.w);
    *reinterpret_cast<s16x8*>(out + i) = o;
}

// ---------- 2) transpose + cast: W (R x C fp32) -> Wt (C x R bf16) ----------
// 128(r) x 64(c) tile per 256-thread block; all 8 float4 loads in flight
// before LDS writes; LDS [c][r] stride 130 (2-way writes / 4-way reads);
// 16B coalesced bf16 stores. Grid (C/64, R/128).
__global__ __launch_bounds__(256) void k_transpose_cast(const float* __restrict__ in,
                                                        u16* __restrict__ out,
                                                        int R, int C) {
    __shared__ float TT[64 * 130];
    const int t = threadIdx.x;
    const int ct = blockIdx.x, rt = blockIdx.y;
    const int tr = t >> 4;          // 0..15
    const int tc = t & 15;          // 0..15
    float4 v[8];
#pragma unroll
    for (int u = 0; u < 8; ++u) {
        int r = u * 16 + tr;
        v[u] = *reinterpret_cast<const float4*>(in + (size_t)(rt * 128 + r) * C + ct * 64 + tc * 4);
    }
#pragma unroll
    for (int u = 0; u < 8; ++u) {
        int r = u * 16 + tr;
        TT[(tc * 4 + 0) * 130 + r] = v[u].x;
        TT[(tc * 4 + 1) * 130 + r] = v[u].y;
        TT[(tc * 4 + 2) * 130 + r] = v[u].z;
        TT[(tc * 4 + 3) * 130 + r] = v[u].w;
    }
    __syncthreads();
#pragma unroll
    for (int u = 0; u < 4; ++u) {
        int oc = u * 16 + tr;
        int r0 = tc * 8;
        s16x8 o;
#pragma unroll
        for (int e = 0; e < 8; ++e)
            o[e] = (short)f32_to_bf16_rne(TT[oc * 130 + r0 + e]);
        *reinterpret_cast<s16x8*>(out + (size_t)(ct * 64 + oc) * R + rt * 128 + r0) = o;
    }
}

// ---------- 3) GEMM m97-style (unchanged — measured at plateau) ----------
template<bool BF16OUT, bool ROPE>
__global__ __launch_bounds__(256) void k_gemm_bt(const u16* __restrict__ Amat,
                                                 const u16* __restrict__ Bt,
                                                 void* __restrict__ Cout,
                                                 int M, int N, int K) {
    __shared__ __align__(16) u16 As[128 * 64];
    __shared__ __align__(16) u16 Bs[128 * 64];
    const int t = threadIdx.x;
    const int lane = t & 63, wave = t >> 6;
    const int m16 = lane & 15, qd = lane >> 4;
    const int wm = (wave >> 1) * 64, wn = (wave & 1) * 64;
    const size_t m0 = (size_t)blockIdx.y * 128, n0 = (size_t)blockIdx.x * 128;
    const int srow = lane >> 3;
    const int schunk = (lane & 7) ^ srow;

    f32x4 acc[4][4] = {};

    for (int k0 = 0; k0 < K; k0 += 64) {
#pragma unroll
        for (int j = 0; j < 4; ++j) {
            int rbase = j * 32 + wave * 8;
            int r = rbase + srow;
            gl2lds16(Amat + (m0 + r) * (size_t)K + k0 + schunk * 8, &As[rbase * 64]);
            gl2lds16(Bt   + (n0 + r) * (size_t)K + k0 + schunk * 8, &Bs[rbase * 64]);
        }
        __syncthreads();
#pragma unroll
        for (int kh = 0; kh < 2; ++kh) {
            s16x8 af[4], bf[4];
#pragma unroll
            for (int i = 0; i < 4; ++i) {
                int ra = wm + i * 16 + m16;
                int pa = (kh * 4 + qd) ^ (ra & 7);
                af[i] = *reinterpret_cast<const s16x8*>(&As[ra * 64 + pa * 8]);
                int rb = wn + i * 16 + m16;
                int pb = (kh * 4 + qd) ^ (rb & 7);
                bf[i] = *reinterpret_cast<const s16x8*>(&Bs[rb * 64 + pb * 8]);
            }
#pragma unroll
            for (int i = 0; i < 4; ++i)
#pragma unroll
                for (int jj = 0; jj < 4; ++jj)
                    acc[i][jj] = __builtin_amdgcn_mfma_f32_16x16x32_bf16(af[i], bf[jj], acc[i][jj], 0, 0, 0);
        }
        __syncthreads();
    }
    if (ROPE && n0 < 4096) {
        float invf[4];
#pragma unroll
        for (int j = 0; j < 4; ++j) {
            int pi = ((int)(wn + j * 16 + m16) & 127) >> 1;
            invf[j] = __expf(-0.14391156831f * (float)pi);
        }
#pragma unroll
        for (int i = 0; i < 4; ++i)
#pragma unroll
            for (int j = 0; j < 4; ++j)
#pragma unroll
                for (int r = 0; r < 4; ++r) {
                    float v = acc[i][j][r];
                    float p = __shfl_xor(v, 1);
                    size_t row = m0 + wm + i * 16 + qd * 4 + r;
                    float f = (float)(int)(row & 2047) * invf[j];
                    float sn, cs;
                    __sincosf(f, &sn, &cs);
                    float res = (m16 & 1) ? fmaf(p, sn, v * cs) : fmaf(v, cs, -p * sn);
                    size_t col = n0 + wn + j * 16 + m16;
                    ((u16*)Cout)[row * N + col] = f32_to_bf16_rne(res);
                }
    } else {
#pragma unroll
        for (int i = 0; i < 4; ++i)
#pragma unroll
            for (int j = 0; j < 4; ++j)
#pragma unroll
                for (int r = 0; r < 4; ++r) {
                    size_t row = m0 + wm + i * 16 + qd * 4 + r;
                    size_t col = n0 + wn + j * 16 + m16;
                    if (BF16OUT)
                        ((u16*)Cout)[row * N + col] = f32_to_bf16_rne(acc[i][j][r]);
                    else
                        ((float*)Cout)[row * N + col] = acc[i][j][r];
                }
    }
}

// ---------- 4) V -> V^T: 128(s) x 128(d) bf16 tile, deep-ILP, 16B both ways ----------
// Grid (16 s-tiles, 32 bh). LDS [d][s] stride 130.
__global__ __launch_bounds__(256) void k_transpose_v(const u16* __restrict__ qkv,
                                                     u16* __restrict__ vt) {
    __shared__ u16 TT[128 * 130];
    const int t = threadIdx.x;
    const int st = blockIdx.x;
    const int bh = blockIdx.y;
    const int b = bh >> 4, h = bh & 15;
    const u16* src = qkv + (size_t)b * 2048 * 6144 + 4096 + (size_t)h * 128;
    const int tr = t >> 4, tc = t & 15;
    s16x8 v[8];
#pragma unroll
    for (int u = 0; u < 8; ++u) {
        int s = u * 16 + tr;
        v[u] = *reinterpret_cast<const s16x8*>(src + (size_t)(st * 128 + s) * 6144 + tc * 8);
    }
#pragma unroll
    for (int u = 0; u < 8; ++u) {
        int s = u * 16 + tr;
#pragma unroll
        for (int e = 0; e < 8; ++e)
            TT[(tc * 8 + e) * 130 + s] = (u16)v[u][e];
    }
    __syncthreads();
    u16* dst = vt + (size_t)bh * 128 * 2048 + st * 128;
#pragma unroll
    for (int u = 0; u < 8; ++u) {
        int d = u * 16 + tr;
        int s0 = tc * 8;
        s16x8 o;
#pragma unroll
        for (int e = 0; e < 8; ++e) o[e] = (short)TT[d * 130 + s0 + e];
        *reinterpret_cast<s16x8*>(dst + (size_t)d * 2048 + s0) = o;
    }
}

// ---------- 5) flash attention (unchanged from R5 — protected win) ----------
__global__ __launch_bounds__(512, 4) void k_flash(const u16* __restrict__ qkv,
                                                  const u16* __restrict__ vt,
                                                  u16* __restrict__ out) {
    __shared__ __align__(16) u16 KS[128 * 136];
    __shared__ __align__(16) u16 VS[128 * 136];
    const int t = threadIdx.x, lane = t & 63, wave = t >> 6;
    const int m16 = lane & 15, qd = lane >> 4;
    const int bh = blockIdx.y, b = bh >> 4, h = bh & 15;
    const int q0 = blockIdx.x * 128;
    const u16* Qg = qkv + (size_t)b * 2048 * 6144 + (size_t)h * 128;
    const u16* Kg = Qg + 2048;
    const u16* Vtg = vt + (size_t)bh * 128 * 2048;
    const float C2 = 0.12751743f;   // (1/sqrt(128)) * log2(e)

    int srow[4], scol[4], pi0[4];
#pragma unroll
    for (int ci = 0; ci < 4; ++ci) {
        int idx = ci * 512 + t;
        int row = idx >> 4, c = idx & 15;
        srow[ci] = row;
        scol[ci] = c * 8;
        pi0[ci] = 32 * (c >> 2) + 16 * (c & 1) + 4 * ((c >> 1) & 1);
    }

    s16x8 qf[4];
#pragma unroll
    for (int kc = 0; kc < 4; ++kc)
        qf[kc] = *reinterpret_cast<const s16x8*>(
            Qg + (size_t)(q0 + wave * 16 + m16) * 6144 + kc * 32 + qd * 8);

    f32x4 accO[8] = {};
    float mrow = -1e30f, lrow = 0.f;

    for (int kt = 0; kt < 16; ++kt) {
        const int s0 = kt * 128;
        s16x8 kreg[4], vreg[4];
#pragma unroll
        for (int ci = 0; ci < 4; ++ci) {
            kreg[ci] = *reinterpret_cast<const s16x8*>(
                Kg + (size_t)(s0 + srow[ci]) * 6144 + scol[ci]);
            vreg[ci] = *reinterpret_cast<const s16x8*>(
                Vtg + (size_t)srow[ci] * 2048 + s0 + scol[ci]);
        }
        __syncthreads();
#pragma unroll
        for (int ci = 0; ci < 4; ++ci) {
            *reinterpret_cast<s16x8*>(&KS[srow[ci] * 136 + scol[ci]]) = kreg[ci];
            s16x4 lo = __builtin_shufflevector(vreg[ci], vreg[ci], 0, 1, 2, 3);
            s16x4 hi = __builtin_shufflevector(vreg[ci], vreg[ci], 4, 5, 6, 7);
            *reinterpret_cast<s16x4*>(&VS[srow[ci] * 136 + pi0[ci]]) = lo;
            *reinterpret_cast<s16x4*>(&VS[srow[ci] * 136 + pi0[ci] + 8]) = hi;
        }
        __syncthreads();

        f32x4 accS[8] = {};
#pragma unroll
        for (int kc = 0; kc < 4; ++kc)
#pragma unroll
            for (int nj = 0; nj < 8; ++nj) {
                s16x8 kf = *reinterpret_cast<const s16x8*>(
                    &KS[(nj * 16 + m16) * 136 + (kc * 4 + qd) * 8]);
                accS[nj] = __builtin_amdgcn_mfma_f32_16x16x32_bf16(kf, qf[kc], accS[nj], 0, 0, 0);
            }

        float mx = accS[0][0];
#pragma unroll
        for (int nj = 0; nj < 8; ++nj)
#pragma unroll
            for (int r = 0; r < 4; ++r) mx = fmaxf(mx, accS[nj][r]);
        mx *= C2;
        mx = fmaxf(mx, __shfl_xor(mx, 16));
        mx = fmaxf(mx, __shfl_xor(mx, 32));
        float mn = fmaxf(mrow, mx);
        float alpha = __builtin_amdgcn_exp2f(mrow - mn);
        mrow = mn;
        float ls = 0.f;
        s16x4 pk[8];
#pragma unroll
        for (int nj = 0; nj < 8; ++nj) {
            float p0 = __builtin_amdgcn_exp2f(fmaf(accS[nj][0], C2, -mn));
            float p1 = __builtin_amdgcn_exp2f(fmaf(accS[nj][1], C2, -mn));
            float p2 = __builtin_amdgcn_exp2f(fmaf(accS[nj][2], C2, -mn));
            float p3 = __builtin_amdgcn_exp2f(fmaf(accS[nj][3], C2, -mn));
            ls += (p0 + p1) + (p2 + p3);
            u32 lo = pack_bf16_rhu(p0, p1);
            u32 hi = pack_bf16_rhu(p2, p3);
            uint2 pr = make_uint2(lo, hi);
            pk[nj] = __builtin_bit_cast(s16x4, pr);
        }
        ls += __shfl_xor(ls, 16);
        ls += __shfl_xor(ls, 32);
        lrow = lrow * alpha + ls;
        float aO[4];
#pragma unroll
        for (int r = 0; r < 4; ++r) aO[r] = __shfl(alpha, qd * 4 + r);
#pragma unroll
        for (int dj = 0; dj < 8; ++dj)
#pragma unroll
            for (int r = 0; r < 4; ++r) accO[dj][r] *= aO[r];

#pragma unroll
        for (int kb = 0; kb < 4; ++kb) {
            s16x8 af = __builtin_shufflevector(pk[2 * kb], pk[2 * kb + 1],
                                               0, 1, 2, 3, 4, 5, 6, 7);
#pragma unroll
            for (int dj = 0; dj < 8; ++dj) {
                s16x8 vf = *reinterpret_cast<const s16x8*>(
                    &VS[(dj * 16 + m16) * 136 + kb * 32 + qd * 8]);
                accO[dj] = __builtin_amdgcn_mfma_f32_16x16x32_bf16(af, vf, accO[dj], 0, 0, 0);
            }
        }
    }
    float invl = 1.0f / lrow;
    float iv[4];
#pragma unroll
    for (int r = 0; r < 4; ++r) iv[r] = __shfl(invl, qd * 4 + r);
#pragma unroll
    for (int r = 0; r < 4; ++r) {
        size_t row = (size_t)b * 2048 + q0 + wave * 16 + qd * 4 + r;
#pragma unroll
        for (int dj = 0; dj < 8; ++dj)
            out[row * 2048 + h * 128 + dj * 16 + m16] =
                f32_to_bf16_rne(accO[dj][r] * iv[r]);
    }
}

// ---------- launch ----------
extern "C" void kernel_launch(void* const* d_in, const int* in_sizes, int n_in,
                              void* d_out, int out_size, void* d_ws, size_t ws_size,
                              hipStream_t stream) {
    const float* x     = (const float*)d_in[0];
    const float* W_qkv = (const float*)d_in[1];
    const float* W_out = (const float*)d_in[2];
    float* out = (float*)d_out;

    char* ws = (char*)d_ws;
    u16* xb   = (u16*)(ws);
    u16* Wqt  = (u16*)(ws + (16u << 20));
    u16* Wot  = (u16*)(ws + (40u << 20));
    u16* qkvb = (u16*)(ws + (48u << 20));
    u16* attn = (u16*)(ws + (96u << 20));
    u16* vtg  = (u16*)(ws + (112u << 20));

    k_cast<<<4096, 256, 0, stream>>>(x, xb);
    k_transpose_cast<<<dim3(96, 16), 256, 0, stream>>>(W_qkv, Wqt, 2048, 6144);
    k_transpose_cast<<<dim3(32, 16), 256, 0, stream>>>(W_out, Wot, 2048, 2048);
    k_gemm_bt<true, true><<<dim3(48, 32), 256, 0, stream>>>(xb, Wqt, qkvb, 4096, 6144, 2048);
    k_transpose_v<<<dim3(16, 32), 256, 0, stream>>>(qkvb, vtg);
    k_flash<<<dim3(16, 32), 512, 0, stream>>>(qkvb, vtg, attn);
    k_gemm_bt<false, false><<<dim3(16, 32), 256, 0, stream>>>(attn, Wot, out, 4096, 2048, 2048);
}